// Round 18
// baseline (111.862 us; speedup 1.0000x reference)
//
#include <hip/hip_runtime.h>

typedef __attribute__((ext_vector_type(8)))  short bf16x8;
typedef __attribute__((ext_vector_type(4)))  short s16x4;
typedef __attribute__((ext_vector_type(4)))  float f32x4;
typedef __attribute__((ext_vector_type(16))) float f32x16;
typedef __attribute__((ext_vector_type(4)))  unsigned u32x4;

#define B_  2
#define S_  2048
#define H_  16
#define D_  64
#define E_  1024
#define M_  (B_*S_)
#define NH_ (M_*H_)
#define L2E 1.44269504f

__device__ __forceinline__ unsigned short f2bf(float f){
  unsigned x = __builtin_bit_cast(unsigned, f);
  x += 0x7fffu + ((x >> 16) & 1u);
  return (unsigned short)(x >> 16);
}
__device__ __forceinline__ unsigned pk_bf16(float lo, float hi){
  unsigned short a = __builtin_bit_cast(unsigned short, (__bf16)lo);
  unsigned short b = __builtin_bit_cast(unsigned short, (__bf16)hi);
  return (unsigned)a | ((unsigned)b << 16);
}

#define GLD16(gp, lp) __builtin_amdgcn_global_load_lds( \
    (const __attribute__((address_space(1))) unsigned*)(gp), \
    (__attribute__((address_space(3))) unsigned*)(lp), 16, 0, 0)

// ---------------- fused prep: x->bf16 + RoPE/mask tables | W^T bf16 ----------------
__global__ __launch_bounds__(256) void k_prep(const float* __restrict__ in, short* __restrict__ out,
                                              const float* __restrict__ mask,
                                              float* ct, float* st, float* maskC,
                                              const float* __restrict__ Wq, const float* __restrict__ Wk,
                                              const float* __restrict__ Wv, short* __restrict__ wt){
  const int bx = blockIdx.x;
  if(bx < 4096){
    int i = bx*256 + threadIdx.x;
    if(i < S_*32){                           // RoPE tables [2048][32]
      int s = i >> 5, f = i & 31;
      float invf = powf(10000.0f, -(float)f / 32.0f);
      float ph = (float)s * invf;
      ct[i] = cosf(ph);
      st[i] = sinf(ph);
      if(i < B_*S_) maskC[i] = fmaf(mask[i], L2E, -17.0f);   // log2-domain mask, -17 recenter
    }
    int j = i*4;
    float4 v = *(const float4*)(in + j);
    s16x4 o = { (short)f2bf(v.x), (short)f2bf(v.y), (short)f2bf(v.z), (short)f2bf(v.w) };
    *(s16x4*)(out + j) = o;
  } else {
    int w = bx - 4096;                       // 0..767
    int z = w >> 8, r = w & 255;
    const float* W = z==0 ? Wq : (z==1 ? Wk : Wv);
    short* outw = wt + (size_t)z*E_*E_;
    __shared__ short tile[64][72];
    int nb = (r & 15)*64, kb = (r >> 4)*64;
    int t = threadIdx.x;
    {
      int rr = t>>2, c0 = (t&3)*16;
      const float* src = W + (size_t)(kb+rr)*E_ + nb + c0;
      #pragma unroll
      for(int i=0;i<4;i++){
        float4 v = *(const float4*)(src + i*4);
        tile[rr][c0+i*4+0] = (short)f2bf(v.x);
        tile[rr][c0+i*4+1] = (short)f2bf(v.y);
        tile[rr][c0+i*4+2] = (short)f2bf(v.z);
        tile[rr][c0+i*4+3] = (short)f2bf(v.w);
      }
    }
    __syncthreads();
    {
      int n = t>>2, k0 = (t&3)*16;
      short* dst = outw + (size_t)(nb+n)*E_ + kb + k0;
      bf16x8 o0, o1;
      #pragma unroll
      for(int i=0;i<8;i++){ o0[i] = tile[k0+i][n]; o1[i] = tile[k0+8+i][n]; }
      *(bf16x8*)dst = o0;
      *(bf16x8*)(dst+8) = o1;
    }
  }
}

// ---------------- QKV GEMM, 256x256 tile, 8 waves, 4 quadrant-phases per K-tile ----------------
// dbuf 128KB LDS; staging front-loaded into phases 0-1 (T4); R13-proven XOR swizzle.
__global__ __launch_bounds__(512,2) void k_gemm(const short* __restrict__ A, const short* __restrict__ WT,
                                              const float* __restrict__ biasq, const float* __restrict__ biask,
                                              const float* __restrict__ biasv,
                                              short* __restrict__ oq, short* __restrict__ ok, short* __restrict__ ovt,
                                              const float* __restrict__ cost, const float* __restrict__ sint){
  const int z = blockIdx.z;
  const short* Bw = WT + (size_t)z*E_*E_;
  const float* bias = z==0 ? biasq : (z==1 ? biask : biasv);
  __shared__ short As[2][256*64];   // 64KB
  __shared__ short Bs[2][256*64];   // 64KB
  const int t = threadIdx.x, lane = t & 63, wid = t >> 6;
  const int wr = wid >> 2, wc = wid & 3;           // 2M x 4N wave grid; wave out = 128x64
  const int mb = blockIdx.x*256, nb = blockIdx.y*256;
  const int l15 = lane & 15, lq = lane >> 4;
  f32x4 acc[8][4] = {};

  // prologue: stage K-tile 0 into buf0
  #pragma unroll
  for(int j=0;j<4;j++){
    int c = t + 512*j;
    int row = c>>3;
    int colg = ((c&7) ^ (row&7))*8;                // inverse-swizzled global column group
    GLD16(A  + (size_t)(mb + row)*E_ + colg, &As[0][c*8]);
    GLD16(Bw + (size_t)(nb + row)*E_ + colg, &Bs[0][c*8]);
  }
  __syncthreads();

  for(int kt=0; kt<16; kt++){
    const int cur = kt & 1;
    const short* Asc = As[cur];
    const short* Bsc = Bs[cur];
    short* Asn = As[cur^1];
    short* Bsn = Bs[cur^1];
    const bool pf = (kt+1 < 16);
    #pragma unroll
    for(int ph=0; ph<4; ph++){
      const int mq = ph>>1, nq = ph&1;
      // ---- ds-read quadrant fragments (swizzled cols) ----
      bf16x8 af[4][2], bf[2][2];
      #pragma unroll
      for(int i=0;i<4;i++){
        int r = wr*128 + (mq*4+i)*16 + l15;
        #pragma unroll
        for(int kk=0;kk<2;kk++){
          int c8 = (kk*4 + lq) ^ (r&7);
          af[i][kk] = *(const bf16x8*)&Asc[r*64 + c8*8];
        }
      }
      #pragma unroll
      for(int j2=0;j2<2;j2++){
        int r = wc*64 + (nq*2+j2)*16 + l15;
        #pragma unroll
        for(int kk=0;kk<2;kk++){
          int c8 = (kk*4 + lq) ^ (r&7);
          bf[j2][kk] = *(const bf16x8*)&Bsc[r*64 + c8*8];
        }
      }
      // ---- front-loaded staging: 4 chunks in ph0, 4 in ph1, none in ph2/3 ----
      if(pf && ph < 2){
        #pragma unroll
        for(int j3=0;j3<2;j3++){
          int c = t + 512*(ph*2 + j3);
          int row = c>>3;
          int colg = ((c&7) ^ (row&7))*8;
          GLD16(A  + (size_t)(mb + row)*E_ + (kt+1)*64 + colg, &Asn[c*8]);
          GLD16(Bw + (size_t)(nb + row)*E_ + (kt+1)*64 + colg, &Bsn[c*8]);
        }
      }
      // ---- cluster boundary, then MFMA burst ----
      __builtin_amdgcn_s_barrier();
      asm volatile("s_waitcnt lgkmcnt(0)" ::: "memory");
      __builtin_amdgcn_sched_barrier(0);           // rule #18: pin MFMA after the wait
      __builtin_amdgcn_s_setprio(1);
      #pragma unroll
      for(int i=0;i<4;i++)
        #pragma unroll
        for(int j2=0;j2<2;j2++)
          #pragma unroll
          for(int kk=0;kk<2;kk++)
            acc[mq*4+i][nq*2+j2] = __builtin_amdgcn_mfma_f32_16x16x32_bf16(
                af[i][kk], bf[j2][kk], acc[mq*4+i][nq*2+j2], 0, 0, 0);
      __builtin_amdgcn_s_setprio(0);
      if(ph < 3) __builtin_amdgcn_s_barrier();
    }
    __syncthreads();   // vmcnt(0)+lgkm(0)+barrier: staged tile complete before next reads
  }

  // ---- epilogues (R13 math, 8x4 fragment grid) ----
  const int col16 = l15, rg = lq;
  float bvs[4];
  #pragma unroll
  for(int nf=0; nf<4; nf++) bvs[nf] = bias[nb + wc*64 + nf*16 + col16];
  if(z == 2){
    // direct V^T store: vt[((b*H+h)*D+d)*S + s]; 4 consecutive acc rows = 8B along S
    #pragma unroll
    for(int mf=0; mf<8; mf++){
      int row0 = mb + wr*128 + mf*16 + rg*4;
      int bb2 = row0 >> 11, ss = row0 & (S_-1);
      #pragma unroll
      for(int nf=0; nf<4; nf++){
        int e = nb + wc*64 + nf*16 + col16;
        int hh = e >> 6, dd = e & 63;
        s16x4 w = { (short)f2bf(acc[mf][nf][0]+bvs[nf]), (short)f2bf(acc[mf][nf][1]+bvs[nf]),
                    (short)f2bf(acc[mf][nf][2]+bvs[nf]), (short)f2bf(acc[mf][nf][3]+bvs[nf]) };
        *(s16x4*)(ovt + ((size_t)(bb2*H_+hh)*D_+dd)*S_ + ss) = w;
      }
    }
  } else {
    short* out = (z==0) ? oq : ok;
    // wave col-span = 64 = exactly one head; RoPE pairs (d, d+32) = (nf, nf+2)
    const float qs = (z==0) ? (0.125f*L2E) : 1.0f;   // fold score scale + log2e into q
    #pragma unroll
    for(int mf=0; mf<8; mf++)
      #pragma unroll
      for(int r=0; r<4; r++){
        int row = mb + wr*128 + mf*16 + rg*4 + r;
        int srow = row & (S_-1);
        const float* cb = cost + (size_t)srow*32;
        const float* sb = sint + (size_t)srow*32;
        #pragma unroll
        for(int nf=0; nf<2; nf++){
          int d = nf*16 + col16;
          float c = cb[d], sn = sb[d];
          float x0 = acc[mf][nf][r]   + bvs[nf];
          float x1 = acc[mf][nf+2][r] + bvs[nf+2];
          out[(size_t)row*E_ + nb + wc*64 + nf*16 + col16]     = (short)f2bf((x0*c - x1*sn)*qs);
          out[(size_t)row*E_ + nb + wc*64 + (nf+2)*16 + col16] = (short)f2bf((x1*c + x0*sn)*qs);
        }
      }
  }
}

// ---------------- Flash attention: both KV-splits in ONE 512-thread block ----------------
// 8 waves = 2 groups x 4 q-subtile waves. Each group runs the frozen R13 dbuf loop on its
// own 36.9KB LDS slab (identical barrier counts -> lockstep harmless). Final combine via
// in-block LDS exchange (R5-proven pattern) -> one f32 write, no k_comb, all-f32 sum.
__global__ __launch_bounds__(512,2) void k_attn(
    const short* __restrict__ qg, const short* __restrict__ kg,
    const short* __restrict__ vtg, const float* __restrict__ maskC,
    float* __restrict__ outg){
  __shared__ short smem[2*18432];  // per group: K dbuf 2x4608 + V dbuf 2x4608 shorts = 73728B
  // flat 512 -> XCD-clustered (b,h): xcd = flat&7 hosts bh = xcd*4 + (v>>4)
  const int flat = blockIdx.x;
  const int v = flat >> 3;
  const int bh = (flat & 7)*4 + (v >> 4);
  const int qb = v & 15;
  const int h = bh & 15, b = bh >> 4;
  const int tid = threadIdx.x, wid = tid>>6, lane = tid&63;
  const int grp = wid >> 2, w4 = wid & 3;
  const int l31 = lane & 31, hl = lane >> 5;
  const int qw = qb*128 + w4*32;
  const int tg = tid & 255, rr = tg>>3, ch = tg&7;
  const int kb0 = grp*16;
  const int NT = 16;
  short* base = smem + grp*18432;          // group slab: K[2][4608] then V[2][4608]

  bf16x8 qf[4];
  {
    const short* qp = qg + ((size_t)(b*S_ + qw + l31)*H_ + h)*D_;
    #pragma unroll
    for(int dk=0; dk<4; dk++)
      qf[dk] = *(const bf16x8*)(qp + dk*16 + hl*8);
  }
  f32x16 O0 = {}, O1 = {};
  float l_run = 0.f;
  const float* mrow = maskC + (size_t)b*S_;

  bf16x8 ka, kc, va, vc;
#define LOADT(kb) { \
    const short* ks_ = kg + ((size_t)(b*S_ + (kb)*64 + rr)*H_ + h)*D_ + ch*8; \
    ka = *(const bf16x8*)ks_;  kc = *(const bf16x8*)(ks_ + 32*H_*D_); \
    const short* vs_ = vtg + ((size_t)(b*H_ + h)*D_ + rr)*S_ + (kb)*64 + ch*8; \
    va = *(const bf16x8*)vs_;  vc = *(const bf16x8*)(vs_ + 32*S_); }
#define WRITET(pp) { \
    short* kd = base + (pp)*4608; \
    short* vd = base + 9216 + (pp)*4608; \
    *(bf16x8*)&kd[rr*72 + ch*8]      = ka; \
    *(bf16x8*)&kd[(rr+32)*72 + ch*8] = kc; \
    *(bf16x8*)&vd[rr*72 + ch*8]      = va; \
    *(bf16x8*)&vd[(rr+32)*72 + ch*8] = vc; }

  LOADT(kb0);
  WRITET(0);
  LOADT(kb0+1);
  asm volatile("s_waitcnt lgkmcnt(0)" ::: "memory");
  __builtin_amdgcn_s_barrier();

  int p = 0;
  for(int tt=0; tt<NT; tt++){
    const short* Ksp = base + p*4608;
    const short* Vsp = base + 9216 + p*4608;
    // ---- QK^T: lane holds q-col l31, rows = keys (log2 units) ----
    f32x16 s0 = {}, s1 = {};
    __builtin_amdgcn_s_setprio(1);
    #pragma unroll
    for(int dk=0; dk<4; dk++){
      bf16x8 kf0 = *(const bf16x8*)&Ksp[(l31)*72 + dk*16 + hl*8];
      bf16x8 kf1 = *(const bf16x8*)&Ksp[(32+l31)*72 + dk*16 + hl*8];
      s0 = __builtin_amdgcn_mfma_f32_32x32x16_bf16(kf0, qf[dk], s0, 0,0,0);
      s1 = __builtin_amdgcn_mfma_f32_32x32x16_bf16(kf1, qf[dk], s1, 0,0,0);
    }
    __builtin_amdgcn_s_setprio(0);
    // + log2-domain mask; reg r=a+4*bb -> key = a + 8*bb + 4*hl
    {
      const float* mt = mrow + (kb0+tt)*64 + hl*4;
      #pragma unroll
      for(int bb=0; bb<4; bb++){
        f32x4 mv0 = *(const f32x4*)(mt + bb*8);
        f32x4 mv1 = *(const f32x4*)(mt + 32 + bb*8);
        #pragma unroll
        for(int a=0; a<4; a++){ s0[bb*4+a] += mv0[a]; s1[bb*4+a] += mv1[a]; }
      }
    }
    #pragma unroll
    for(int i=0;i<16;i++) s0[i] = __builtin_amdgcn_exp2f(s0[i]);
    #pragma unroll
    for(int i=0;i<16;i++) s1[i] = __builtin_amdgcn_exp2f(s1[i]);
    float la=0.f, lb=0.f, lc=0.f, ld=0.f;
    #pragma unroll
    for(int i=0;i<4;i++){
      la += s0[i];   lb += s0[4+i];  lc += s0[8+i];  ld += s0[12+i];
      la += s1[i];   lb += s1[4+i];  lc += s1[8+i];  ld += s1[12+i];
    }
    float ls = (la+lb)+(lc+ld);
    ls += __shfl_xor(ls, 32);
    l_run += ls;

    // pack P to bf16 words
    unsigned w0a[8], w1a[8];
    #pragma unroll
    for(int c=0;c<8;c++){
      int bs = (c&3)*4;
      float p0 = (c & 4) ? s1[bs+0] : s0[bs+0];
      float p1 = (c & 4) ? s1[bs+1] : s0[bs+1];
      float p2 = (c & 4) ? s1[bs+2] : s0[bs+2];
      float p3 = (c & 4) ? s1[bs+3] : s0[bs+3];
      w0a[c] = pk_bf16(p0, p1);
      w1a[c] = pk_bf16(p2, p3);
    }

    // ---- stage tile tt+1 into buf p^1 (loads issued a tile ago), issue tt+2 ----
    if(tt+1 < NT){
      WRITET(p^1);
      if(tt+2 < NT) LOADT(kb0+tt+2);
    }

    // ---- PV from buf p ----
    __builtin_amdgcn_s_setprio(1);
    #pragma unroll
    for(int ksl=0; ksl<4; ksl++){
      unsigned a0 = w0a[2*ksl], b0 = w0a[2*ksl+1];
      unsigned a1 = w1a[2*ksl], b1 = w1a[2*ksl+1];
      asm("v_permlane32_swap_b32 %0, %1" : "+v"(a0), "+v"(b0));
      asm("v_permlane32_swap_b32 %0, %1" : "+v"(a1), "+v"(b1));
      u32x4 pw = { a0, a1, b0, b1 };
      bf16x8 pf = __builtin_bit_cast(bf16x8, pw);
      bf16x8 vf0 = *(const bf16x8*)&Vsp[(l31)*72 + ksl*16 + hl*8];
      bf16x8 vf1 = *(const bf16x8*)&Vsp[(32+l31)*72 + ksl*16 + hl*8];
      O0 = __builtin_amdgcn_mfma_f32_32x32x16_bf16(pf, vf0, O0, 0,0,0);
      O1 = __builtin_amdgcn_mfma_f32_32x32x16_bf16(pf, vf1, O1, 0,0,0);
    }
    __builtin_amdgcn_s_setprio(0);
    // barrier drains LDS only; outstanding global prefetch crosses it (T4)
    asm volatile("s_waitcnt lgkmcnt(0)" ::: "memory");
    __builtin_amdgcn_s_barrier();
    p ^= 1;
  }
#undef LOADT
#undef WRITET

  // ---- in-block split combine via LDS (slabs dead): group1 -> group0, all-f32 ----
  __syncthreads();
  float* ex  = (float*)smem;               // [4 waves][32 regs][64 lanes] = 32KB
  float* exl = (float*)smem + 4*32*64;     // [4][32] row sums
  if(grp == 1){
    #pragma unroll
    for(int r=0;r<16;r++){
      ex[(w4*32 + r)*64 + lane]      = O0[r];
      ex[(w4*32 + 16 + r)*64 + lane] = O1[r];
    }
    if(lane < 32) exl[w4*32 + lane] = l_run;
  }
  __syncthreads();
  if(grp == 0){
    #pragma unroll
    for(int r=0;r<16;r++){
      O0[r] += ex[(w4*32 + r)*64 + lane];
      O1[r] += ex[(w4*32 + 16 + r)*64 + lane];
    }
    float linv = 1.f / (l_run + exl[w4*32 + l31]);
    #pragma unroll
    for(int bb=0; bb<4; bb++)
      #pragma unroll
      for(int a=0; a<4; a++){
        float li = __shfl(linv, a + 8*bb + 4*hl);
        int qrow = qw + a + 8*bb + 4*hl;
        float* op = outg + ((size_t)(b*S_ + qrow)*H_ + h)*D_;
        op[l31]      = O0[bb*4+a] * li;
        op[32 + l31] = O1[bb*4+a] * li;
      }
  }
}

extern "C" void kernel_launch(void* const* d_in, const int* in_sizes, int n_in,
                              void* d_out, int out_size, void* d_ws, size_t ws_size,
                              hipStream_t stream){
  (void)in_sizes; (void)n_in; (void)out_size; (void)ws_size;
  const float* x    = (const float*)d_in[0];
  const float* mask = (const float*)d_in[1];
  const float* Wq   = (const float*)d_in[2];
  const float* bq   = (const float*)d_in[3];
  const float* Wk   = (const float*)d_in[4];
  const float* bk   = (const float*)d_in[5];
  const float* Wv   = (const float*)d_in[6];
  const float* bv   = (const float*)d_in[7];
  float* out = (float*)d_out;
  char* ws = (char*)d_ws;
  // ws map (40 MiB proven envelope):
  float* cost  = (float*)(ws);                   // 256K
  float* sint  = (float*)(ws + (256u<<10));      // 256K
  float* maskC = (float*)(ws + (512u<<10));      // 16K
  short* xb    = (short*)(ws + (2u<<20));        // 8M  x bf16
  short* wt    = (short*)(ws + (10u<<20));       // 6M  W^T bf16
  short* qb    = (short*)(ws + (16u<<20));       // 8M  q bf16
  short* kb    = (short*)(ws + (24u<<20));       // 8M  k bf16
  short* vtb   = (short*)(ws + (32u<<20));       // 8M  V^T bf16

  k_prep<<<dim3(4096+768), dim3(256), 0, stream>>>(x, xb, mask, cost, sint, maskC,
                                                   Wq, Wk, Wv, wt);
  k_gemm<<<dim3(16,4,3), dim3(512), 0, stream>>>(xb, wt, bq, bk, bv, qb, kb, vtb, cost, sint);
  k_attn<<<dim3(512), dim3(512), 0, stream>>>(qb, kb, vtb, maskC, out);
}

// Round 19
// 111.369 us; speedup vs baseline: 1.0044x; 1.0044x over previous
//
#include <hip/hip_runtime.h>

typedef __attribute__((ext_vector_type(8)))  short bf16x8;
typedef __attribute__((ext_vector_type(4)))  short s16x4;
typedef __attribute__((ext_vector_type(4)))  float f32x4;
typedef __attribute__((ext_vector_type(16))) float f32x16;
typedef __attribute__((ext_vector_type(4)))  unsigned u32x4;
typedef __attribute__((ext_vector_type(4)))  _Float16 f16x4;

#define B_  2
#define S_  2048
#define H_  16
#define D_  64
#define E_  1024
#define M_  (B_*S_)
#define NH_ (M_*H_)
#define L2E 1.44269504f

__device__ __forceinline__ unsigned short f2bf(float f){
  unsigned x = __builtin_bit_cast(unsigned, f);
  x += 0x7fffu + ((x >> 16) & 1u);
  return (unsigned short)(x >> 16);
}
__device__ __forceinline__ unsigned pk_bf16(float lo, float hi){
  unsigned short a = __builtin_bit_cast(unsigned short, (__bf16)lo);
  unsigned short b = __builtin_bit_cast(unsigned short, (__bf16)hi);
  return (unsigned)a | ((unsigned)b << 16);
}

#define GLD16(gp, lp) __builtin_amdgcn_global_load_lds( \
    (const __attribute__((address_space(1))) unsigned*)(gp), \
    (__attribute__((address_space(3))) unsigned*)(lp), 16, 0, 0)

// ---------------- fused prep: x->bf16 + RoPE/mask tables | W^T bf16 ----------------
__global__ __launch_bounds__(256) void k_prep(const float* __restrict__ in, short* __restrict__ out,
                                              const float* __restrict__ mask,
                                              float* ct, float* st, float* maskC,
                                              const float* __restrict__ Wq, const float* __restrict__ Wk,
                                              const float* __restrict__ Wv, short* __restrict__ wt){
  const int bx = blockIdx.x;
  if(bx < 4096){
    int i = bx*256 + threadIdx.x;
    if(i < S_*32){                           // RoPE tables [2048][32]
      int s = i >> 5, f = i & 31;
      float invf = powf(10000.0f, -(float)f / 32.0f);
      float ph = (float)s * invf;
      ct[i] = cosf(ph);
      st[i] = sinf(ph);
      if(i < B_*S_) maskC[i] = fmaf(mask[i], L2E, -17.0f);   // log2-domain mask, -17 recenter
    }
    int j = i*4;
    float4 v = *(const float4*)(in + j);
    s16x4 o = { (short)f2bf(v.x), (short)f2bf(v.y), (short)f2bf(v.z), (short)f2bf(v.w) };
    *(s16x4*)(out + j) = o;
  } else {
    int w = bx - 4096;                       // 0..767
    int z = w >> 8, r = w & 255;
    const float* W = z==0 ? Wq : (z==1 ? Wk : Wv);
    short* outw = wt + (size_t)z*E_*E_;
    __shared__ short tile[64][72];
    int nb = (r & 15)*64, kb = (r >> 4)*64;
    int t = threadIdx.x;
    {
      int rr = t>>2, c0 = (t&3)*16;
      const float* src = W + (size_t)(kb+rr)*E_ + nb + c0;
      #pragma unroll
      for(int i=0;i<4;i++){
        float4 v = *(const float4*)(src + i*4);
        tile[rr][c0+i*4+0] = (short)f2bf(v.x);
        tile[rr][c0+i*4+1] = (short)f2bf(v.y);
        tile[rr][c0+i*4+2] = (short)f2bf(v.z);
        tile[rr][c0+i*4+3] = (short)f2bf(v.w);
      }
    }
    __syncthreads();
    {
      int n = t>>2, k0 = (t&3)*16;
      short* dst = outw + (size_t)(nb+n)*E_ + kb + k0;
      bf16x8 o0, o1;
      #pragma unroll
      for(int i=0;i<8;i++){ o0[i] = tile[k0+i][n]; o1[i] = tile[k0+8+i][n]; }
      *(bf16x8*)dst = o0;
      *(bf16x8*)(dst+8) = o1;
    }
  }
}

// ---------------- QKV GEMM, 256x256 tile, 8 waves, 4 quadrant-phases per K-tile ----------------
// dbuf 128KB LDS; staging front-loaded into phases 0-1 (T4); R13-proven XOR swizzle.
__global__ __launch_bounds__(512,2) void k_gemm(const short* __restrict__ A, const short* __restrict__ WT,
                                              const float* __restrict__ biasq, const float* __restrict__ biask,
                                              const float* __restrict__ biasv,
                                              short* __restrict__ oq, short* __restrict__ ok, short* __restrict__ ovt,
                                              const float* __restrict__ cost, const float* __restrict__ sint){
  const int z = blockIdx.z;
  const short* Bw = WT + (size_t)z*E_*E_;
  const float* bias = z==0 ? biasq : (z==1 ? biask : biasv);
  __shared__ short As[2][256*64];   // 64KB
  __shared__ short Bs[2][256*64];   // 64KB
  const int t = threadIdx.x, lane = t & 63, wid = t >> 6;
  const int wr = wid >> 2, wc = wid & 3;           // 2M x 4N wave grid; wave out = 128x64
  const int mb = blockIdx.x*256, nb = blockIdx.y*256;
  const int l15 = lane & 15, lq = lane >> 4;
  f32x4 acc[8][4] = {};

  // prologue: stage K-tile 0 into buf0
  #pragma unroll
  for(int j=0;j<4;j++){
    int c = t + 512*j;
    int row = c>>3;
    int colg = ((c&7) ^ (row&7))*8;                // inverse-swizzled global column group
    GLD16(A  + (size_t)(mb + row)*E_ + colg, &As[0][c*8]);
    GLD16(Bw + (size_t)(nb + row)*E_ + colg, &Bs[0][c*8]);
  }
  __syncthreads();

  for(int kt=0; kt<16; kt++){
    const int cur = kt & 1;
    const short* Asc = As[cur];
    const short* Bsc = Bs[cur];
    short* Asn = As[cur^1];
    short* Bsn = Bs[cur^1];
    const bool pf = (kt+1 < 16);
    #pragma unroll
    for(int ph=0; ph<4; ph++){
      const int mq = ph>>1, nq = ph&1;
      // ---- ds-read quadrant fragments (swizzled cols) ----
      bf16x8 af[4][2], bf[2][2];
      #pragma unroll
      for(int i=0;i<4;i++){
        int r = wr*128 + (mq*4+i)*16 + l15;
        #pragma unroll
        for(int kk=0;kk<2;kk++){
          int c8 = (kk*4 + lq) ^ (r&7);
          af[i][kk] = *(const bf16x8*)&Asc[r*64 + c8*8];
        }
      }
      #pragma unroll
      for(int j2=0;j2<2;j2++){
        int r = wc*64 + (nq*2+j2)*16 + l15;
        #pragma unroll
        for(int kk=0;kk<2;kk++){
          int c8 = (kk*4 + lq) ^ (r&7);
          bf[j2][kk] = *(const bf16x8*)&Bsc[r*64 + c8*8];
        }
      }
      // ---- front-loaded staging: 4 chunks in ph0, 4 in ph1, none in ph2/3 ----
      if(pf && ph < 2){
        #pragma unroll
        for(int j3=0;j3<2;j3++){
          int c = t + 512*(ph*2 + j3);
          int row = c>>3;
          int colg = ((c&7) ^ (row&7))*8;
          GLD16(A  + (size_t)(mb + row)*E_ + (kt+1)*64 + colg, &Asn[c*8]);
          GLD16(Bw + (size_t)(nb + row)*E_ + (kt+1)*64 + colg, &Bsn[c*8]);
        }
      }
      // ---- cluster boundary, then MFMA burst ----
      __builtin_amdgcn_s_barrier();
      asm volatile("s_waitcnt lgkmcnt(0)" ::: "memory");
      __builtin_amdgcn_sched_barrier(0);           // rule #18: pin MFMA after the wait
      __builtin_amdgcn_s_setprio(1);
      #pragma unroll
      for(int i=0;i<4;i++)
        #pragma unroll
        for(int j2=0;j2<2;j2++)
          #pragma unroll
          for(int kk=0;kk<2;kk++)
            acc[mq*4+i][nq*2+j2] = __builtin_amdgcn_mfma_f32_16x16x32_bf16(
                af[i][kk], bf[j2][kk], acc[mq*4+i][nq*2+j2], 0, 0, 0);
      __builtin_amdgcn_s_setprio(0);
      if(ph < 3) __builtin_amdgcn_s_barrier();
    }
    __syncthreads();   // vmcnt(0)+lgkm(0)+barrier: staged tile complete before next reads
  }

  // ---- epilogues (R13 math, 8x4 fragment grid) ----
  const int col16 = l15, rg = lq;
  float bvs[4];
  #pragma unroll
  for(int nf=0; nf<4; nf++) bvs[nf] = bias[nb + wc*64 + nf*16 + col16];
  if(z == 2){
    // direct V^T store: vt[((b*H+h)*D+d)*S + s]; 4 consecutive acc rows = 8B along S
    #pragma unroll
    for(int mf=0; mf<8; mf++){
      int row0 = mb + wr*128 + mf*16 + rg*4;
      int bb2 = row0 >> 11, ss = row0 & (S_-1);
      #pragma unroll
      for(int nf=0; nf<4; nf++){
        int e = nb + wc*64 + nf*16 + col16;
        int hh = e >> 6, dd = e & 63;
        s16x4 w = { (short)f2bf(acc[mf][nf][0]+bvs[nf]), (short)f2bf(acc[mf][nf][1]+bvs[nf]),
                    (short)f2bf(acc[mf][nf][2]+bvs[nf]), (short)f2bf(acc[mf][nf][3]+bvs[nf]) };
        *(s16x4*)(ovt + ((size_t)(bb2*H_+hh)*D_+dd)*S_ + ss) = w;
      }
    }
  } else {
    short* out = (z==0) ? oq : ok;
    // wave col-span = 64 = exactly one head; RoPE pairs (d, d+32) = (nf, nf+2)
    const float qs = (z==0) ? (0.125f*L2E) : 1.0f;   // fold score scale + log2e into q
    #pragma unroll
    for(int mf=0; mf<8; mf++)
      #pragma unroll
      for(int r=0; r<4; r++){
        int row = mb + wr*128 + mf*16 + rg*4 + r;
        int srow = row & (S_-1);
        const float* cb = cost + (size_t)srow*32;
        const float* sb = sint + (size_t)srow*32;
        #pragma unroll
        for(int nf=0; nf<2; nf++){
          int d = nf*16 + col16;
          float c = cb[d], sn = sb[d];
          float x0 = acc[mf][nf][r]   + bvs[nf];
          float x1 = acc[mf][nf+2][r] + bvs[nf+2];
          out[(size_t)row*E_ + nb + wc*64 + nf*16 + col16]     = (short)f2bf((x0*c - x1*sn)*qs);
          out[(size_t)row*E_ + nb + wc*64 + (nf+2)*16 + col16] = (short)f2bf((x1*c + x0*sn)*qs);
        }
      }
  }
}

// ---------------- Flash attention, split-KV x2, dbuf LDS (R13 loop, frozen) ----------------
// wide=1 (ws>=48M, proven R14): BOTH partials stored f16 into disjoint scratch buffers
// (p0g/p1g) -> comb reads 16MB not 24MB. wide=0 fallback = exact R16 behavior.
__global__ __launch_bounds__(256,4) void k_attn(
    const short* __restrict__ qg, const short* __restrict__ kg,
    const short* __restrict__ vtg, const float* __restrict__ maskC,
    float* __restrict__ o0g, _Float16* __restrict__ p0g, _Float16* __restrict__ p1g,
    float* __restrict__ lpart, int wide){
  __shared__ short Ks[2][64*72];   // [buf][key][d] pad-72
  __shared__ short Vs[2][64*72];   // [buf][d][key] pad-72
  // flat 1024 -> XCD-clustered (b,h): xcd = flat&7 hosts bh = xcd*4 + (v>>5)
  const int flat = blockIdx.x;
  const int v = flat >> 3;
  const int bh = (flat & 7)*4 + (v >> 5);
  const int inner = v & 31;
  const int qb = inner >> 1, sp = inner & 1;
  const int h = bh & 15, b = bh >> 4;
  const int tid = threadIdx.x, wid = tid>>6, lane = tid&63;
  const int l31 = lane & 31, hl = lane >> 5;
  const int qw = qb*128 + wid*32;
  const int rr = tid>>3, ch = tid&7;
  const int kb0 = sp*16;
  const int NT = 16;

  bf16x8 qf[4];
  {
    const short* qp = qg + ((size_t)(b*S_ + qw + l31)*H_ + h)*D_;
    #pragma unroll
    for(int dk=0; dk<4; dk++)
      qf[dk] = *(const bf16x8*)(qp + dk*16 + hl*8);
  }
  f32x16 O0 = {}, O1 = {};
  float l_run = 0.f;
  const float* mrow = maskC + (size_t)b*S_;

  bf16x8 ka, kc, va, vc;
#define LOADT(kb) { \
    const short* ks_ = kg + ((size_t)(b*S_ + (kb)*64 + rr)*H_ + h)*D_ + ch*8; \
    ka = *(const bf16x8*)ks_;  kc = *(const bf16x8*)(ks_ + 32*H_*D_); \
    const short* vs_ = vtg + ((size_t)(b*H_ + h)*D_ + rr)*S_ + (kb)*64 + ch*8; \
    va = *(const bf16x8*)vs_;  vc = *(const bf16x8*)(vs_ + 32*S_); }
#define WRITET(pp) { \
    *(bf16x8*)&Ks[pp][rr*72 + ch*8]      = ka; \
    *(bf16x8*)&Ks[pp][(rr+32)*72 + ch*8] = kc; \
    *(bf16x8*)&Vs[pp][rr*72 + ch*8]      = va; \
    *(bf16x8*)&Vs[pp][(rr+32)*72 + ch*8] = vc; }

  LOADT(kb0);
  WRITET(0);
  LOADT(kb0+1);
  asm volatile("s_waitcnt lgkmcnt(0)" ::: "memory");
  __builtin_amdgcn_s_barrier();

  int p = 0;
  for(int tt=0; tt<NT; tt++){
    // ---- QK^T from buf p: lane holds q-col l31, rows = keys (log2 units) ----
    f32x16 s0 = {}, s1 = {};
    __builtin_amdgcn_s_setprio(1);
    #pragma unroll
    for(int dk=0; dk<4; dk++){
      bf16x8 kf0 = *(const bf16x8*)&Ks[p][(l31)*72 + dk*16 + hl*8];
      bf16x8 kf1 = *(const bf16x8*)&Ks[p][(32+l31)*72 + dk*16 + hl*8];
      s0 = __builtin_amdgcn_mfma_f32_32x32x16_bf16(kf0, qf[dk], s0, 0,0,0);
      s1 = __builtin_amdgcn_mfma_f32_32x32x16_bf16(kf1, qf[dk], s1, 0,0,0);
    }
    __builtin_amdgcn_s_setprio(0);
    // + log2-domain mask; reg r=a+4*bb -> key = a + 8*bb + 4*hl
    {
      const float* mt = mrow + (kb0+tt)*64 + hl*4;
      #pragma unroll
      for(int bb=0; bb<4; bb++){
        f32x4 mv0 = *(const f32x4*)(mt + bb*8);
        f32x4 mv1 = *(const f32x4*)(mt + 32 + bb*8);
        #pragma unroll
        for(int a=0; a<4; a++){ s0[bb*4+a] += mv0[a]; s1[bb*4+a] += mv1[a]; }
      }
    }
    #pragma unroll
    for(int i=0;i<16;i++) s0[i] = __builtin_amdgcn_exp2f(s0[i]);
    #pragma unroll
    for(int i=0;i<16;i++) s1[i] = __builtin_amdgcn_exp2f(s1[i]);
    float la=0.f, lb=0.f, lc=0.f, ld=0.f;
    #pragma unroll
    for(int i=0;i<4;i++){
      la += s0[i];   lb += s0[4+i];  lc += s0[8+i];  ld += s0[12+i];
      la += s1[i];   lb += s1[4+i];  lc += s1[8+i];  ld += s1[12+i];
    }
    float ls = (la+lb)+(lc+ld);
    ls += __shfl_xor(ls, 32);
    l_run += ls;

    // pack P to bf16 words
    unsigned w0a[8], w1a[8];
    #pragma unroll
    for(int c=0;c<8;c++){
      int base = (c&3)*4;
      float p0 = (c & 4) ? s1[base+0] : s0[base+0];
      float p1 = (c & 4) ? s1[base+1] : s0[base+1];
      float p2 = (c & 4) ? s1[base+2] : s0[base+2];
      float p3 = (c & 4) ? s1[base+3] : s0[base+3];
      w0a[c] = pk_bf16(p0, p1);
      w1a[c] = pk_bf16(p2, p3);
    }

    // ---- stage tile tt+1 into buf p^1 (loads issued a tile ago), issue tt+2 ----
    if(tt+1 < NT){
      WRITET(p^1);
      if(tt+2 < NT) LOADT(kb0+tt+2);
    }

    // ---- PV from buf p ----
    __builtin_amdgcn_s_setprio(1);
    #pragma unroll
    for(int ksl=0; ksl<4; ksl++){
      unsigned a0 = w0a[2*ksl], b0 = w0a[2*ksl+1];
      unsigned a1 = w1a[2*ksl], b1 = w1a[2*ksl+1];
      asm("v_permlane32_swap_b32 %0, %1" : "+v"(a0), "+v"(b0));
      asm("v_permlane32_swap_b32 %0, %1" : "+v"(a1), "+v"(b1));
      u32x4 pw = { a0, a1, b0, b1 };
      bf16x8 pf = __builtin_bit_cast(bf16x8, pw);
      bf16x8 vf0 = *(const bf16x8*)&Vs[p][(l31)*72 + ksl*16 + hl*8];
      bf16x8 vf1 = *(const bf16x8*)&Vs[p][(32+l31)*72 + ksl*16 + hl*8];
      O0 = __builtin_amdgcn_mfma_f32_32x32x16_bf16(pf, vf0, O0, 0,0,0);
      O1 = __builtin_amdgcn_mfma_f32_32x32x16_bf16(pf, vf1, O1, 0,0,0);
    }
    __builtin_amdgcn_s_setprio(0);
    // barrier drains LDS only; outstanding global prefetch crosses it (T4)
    asm volatile("s_waitcnt lgkmcnt(0)" ::: "memory");
    __builtin_amdgcn_s_barrier();
    p ^= 1;
  }
#undef LOADT
#undef WRITET

  // raw partial store into DISJOINT buffers; k_comb divides by l0+l1
  if(sp == 0){
    if(wide){
      #pragma unroll
      for(int bb=0; bb<4; bb++)
        #pragma unroll
        for(int a=0; a<4; a++){
          int qrow = qw + a + 8*bb + 4*hl;
          _Float16* op = p0g + ((size_t)(b*S_ + qrow)*H_ + h)*D_;
          op[l31]      = (_Float16)O0[bb*4+a];
          op[32 + l31] = (_Float16)O1[bb*4+a];
        }
    } else {
      #pragma unroll
      for(int bb=0; bb<4; bb++)
        #pragma unroll
        for(int a=0; a<4; a++){
          int qrow = qw + a + 8*bb + 4*hl;
          float* op = o0g + ((size_t)(b*S_ + qrow)*H_ + h)*D_;
          op[l31]      = O0[bb*4+a];
          op[32 + l31] = O1[bb*4+a];
        }
    }
  } else {
    #pragma unroll
    for(int bb=0; bb<4; bb++)
      #pragma unroll
      for(int a=0; a<4; a++){
        int qrow = qw + a + 8*bb + 4*hl;
        _Float16* op = p1g + ((size_t)(b*S_ + qrow)*H_ + h)*D_;
        op[l31]      = (_Float16)O0[bb*4+a];
        op[32 + l31] = (_Float16)O1[bb*4+a];
      }
  }
  if(lane < 32)
    lpart[(size_t)sp*NH_ + (size_t)(b*S_ + qw + l31)*H_ + h] = l_run;
}

// ---------------- combine: out = (P0 + P1) / (l0 + l1) ----------------
__global__ __launch_bounds__(256) void k_comb(float* __restrict__ out, const _Float16* __restrict__ p0,
                                              const _Float16* __restrict__ p1,
                                              const float* __restrict__ lpart, int wide){
  int i = blockIdx.x*256 + threadIdx.x;
  int idx = i*4;
  int lidx = idx >> 6;                       // (b*S+q)*H + h
  float linv = 1.f / (lpart[lidx] + lpart[NH_ + lidx]);
  f16x4 q1 = *(const f16x4*)(p1 + idx);
  f32x4 r;
  if(wide){
    f16x4 q0 = *(const f16x4*)(p0 + idx);
    #pragma unroll
    for(int j=0;j<4;j++) r[j] = ((float)q0[j] + (float)q1[j]) * linv;
  } else {
    f32x4 a = *(f32x4*)(out + idx);
    #pragma unroll
    for(int j=0;j<4;j++) r[j] = (a[j] + (float)q1[j]) * linv;
  }
  *(f32x4*)(out + idx) = r;
}

extern "C" void kernel_launch(void* const* d_in, const int* in_sizes, int n_in,
                              void* d_out, int out_size, void* d_ws, size_t ws_size,
                              hipStream_t stream){
  (void)in_sizes; (void)n_in; (void)out_size;
  const float* x    = (const float*)d_in[0];
  const float* mask = (const float*)d_in[1];
  const float* Wq   = (const float*)d_in[2];
  const float* bq   = (const float*)d_in[3];
  const float* Wk   = (const float*)d_in[4];
  const float* bk   = (const float*)d_in[5];
  const float* Wv   = (const float*)d_in[6];
  const float* bv   = (const float*)d_in[7];
  float* out = (float*)d_out;
  char* ws = (char*)d_ws;
  // ws map: [0,40M) proven; p0 @ [40M,48M) used when ws_size >= 48M (proven by R14 run).
  float* cost  = (float*)(ws);                   // 256K
  float* sint  = (float*)(ws + (256u<<10));      // 256K
  float* maskC = (float*)(ws + (512u<<10));      // 16K
  float* lpart = (float*)(ws + (768u<<10));      // 512K (2 x NH f32)
  short* xb    = (short*)(ws + (2u<<20));        // 8M  x bf16 (aliased by f16 partial p1)
  short* wt    = (short*)(ws + (10u<<20));       // 6M  W^T bf16
  short* qb    = (short*)(ws + (16u<<20));       // 8M  q bf16
  short* kb    = (short*)(ws + (24u<<20));       // 8M  k bf16
  short* vtb   = (short*)(ws + (32u<<20));       // 8M  V^T bf16
  _Float16* p1 = (_Float16*)xb;                  // alias: xb dead after k_gemm
  _Float16* p0 = (_Float16*)(ws + (40u<<20));    // valid iff ws >= 48M

  const int wide = (ws_size >= (size_t)(48u<<20)) ? 1 : 0;

  k_prep<<<dim3(4096+768), dim3(256), 0, stream>>>(x, xb, mask, cost, sint, maskC,
                                                   Wq, Wk, Wv, wt);
  k_gemm<<<dim3(16,4,3), dim3(512), 0, stream>>>(xb, wt, bq, bk, bv, qb, kb, vtb, cost, sint);
  k_attn<<<dim3(1024), dim3(256), 0, stream>>>(qb, kb, vtb, maskC, out, p0, p1, lpart, wide);
  k_comb<<<dim3(4096), dim3(256), 0, stream>>>(out, p0, p1, lpart, wide);
}